// Round 1
// baseline (107.918 us; speedup 1.0000x reference)
//
#include <hip/hip_runtime.h>
#include <hip/hip_bf16.h>
#include <math.h>

// Problem constants
#define BB 8
#define SS 2048
#define DD 768
#define NPOS 512
#define TC 64              // t-chunks for ctx partial reduction (32 t each)
#define SCALE 0.036084391824351615f   // 1/sqrt(768)

// Workspace layout (float offsets, all 16B-aligned)
#define WS_Q      0        // 6144
#define WS_QK     6144     // 6144
#define WS_LI     12288    // 4096  (logits_int [B,NPOS])
#define WS_LOGITS 16384    // 16384 ([B,S], masked -> -inf)
#define WS_ATTN   32768    // 16384
#define WS_CTX    49152    // 6144
#define WS_QBK    55296    // 8
#define WS_PART   55360    // 8*64*768 = 393216
// total = 448576 floats = 1.794 MB

__device__ __forceinline__ float wave_reduce_sum(float v) {
    #pragma unroll
    for (int off = 32; off > 0; off >>= 1) v += __shfl_xor(v, off, 64);
    return v;
}

// out[b*768+d] = dot(vecs + b*vstride, W[d,:]) + bias[d]
// wave-per-output dot. Used for q (vecs=x rows s=0) and final out (vecs=ctx).
__global__ __launch_bounds__(256) void k_gemv(const float* __restrict__ vecs, size_t vstride,
        const float* __restrict__ W, const float* __restrict__ bias,
        float* __restrict__ out) {
    int gw = (blockIdx.x * 256 + threadIdx.x) >> 6;
    int lane = threadIdx.x & 63;
    if (gw >= BB * DD) return;
    int b = gw / DD, d = gw % DD;
    const float4* vr = (const float4*)(vecs + (size_t)b * vstride);
    const float4* wr = (const float4*)(W + (size_t)d * DD);
    float acc = 0.f;
    #pragma unroll
    for (int j = 0; j < 3; ++j) {   // 3*64 float4 = 768 floats
        float4 a = vr[lane + 64 * j];
        float4 w = wr[lane + 64 * j];
        acc += a.x * w.x + a.y * w.y + a.z * w.z + a.w * w.w;
    }
    acc = wave_reduce_sum(acc);
    if (lane == 0) out[gw] = acc + bias[d];
}

// Per batch b: qk[b,e] = sum_d q[b,d]*Wk[d,e]; qbk[b] = q.bk; lint[b,n] = sum_d q[b,d]*pos_emb[d,n]
// grid (5, B): parts 0..2 -> qk chunks of 256 (part 0 also does qbk); parts 3..4 -> lint chunks.
__global__ __launch_bounds__(256) void k_qk(const float* __restrict__ q,
        const float* __restrict__ Wk, const float* __restrict__ bk,
        const float* __restrict__ pos_emb,
        float* __restrict__ qk, float* __restrict__ qbk, float* __restrict__ lint) {
    int part = blockIdx.x, b = blockIdx.y, tid = threadIdx.x;
    __shared__ float qs[DD];
    __shared__ float red[256];
    for (int i = tid; i < DD; i += 256) qs[i] = q[b * DD + i];
    __syncthreads();
    if (part < 3) {
        int e = part * 256 + tid;
        float acc = 0.f;
        #pragma unroll 4
        for (int d = 0; d < DD; ++d) acc += qs[d] * Wk[(size_t)d * DD + e];
        qk[b * DD + e] = acc;
        if (part == 0) {
            float p = 0.f;
            for (int i = tid; i < DD; i += 256) p += qs[i] * bk[i];
            red[tid] = p;
            __syncthreads();
            for (int s2 = 128; s2 > 0; s2 >>= 1) {
                if (tid < s2) red[tid] += red[tid + s2];
                __syncthreads();
            }
            if (tid == 0) qbk[b] = red[0];
        }
    } else {
        int n = (part - 3) * 256 + tid;
        float acc = 0.f;
        #pragma unroll 4
        for (int d = 0; d < DD; ++d) acc += qs[d] * pos_emb[(size_t)d * NPOS + n];
        lint[b * NPOS + n] = acc;
    }
}

// logits[b,t] = scale * (x[b,t,:].qk[b,:] + qbk[b]); masked -> -inf. Wave per row.
__global__ __launch_bounds__(256) void k_logits(const float* __restrict__ x,
        const float* __restrict__ qk, const float* __restrict__ qbk,
        const int* __restrict__ mask, float* __restrict__ logits) {
    int gw = (blockIdx.x * 256 + threadIdx.x) >> 6;
    int lane = threadIdx.x & 63;
    if (gw >= BB * SS) return;
    int b = gw / SS;
    const float4* xr = (const float4*)(x + (size_t)gw * DD);
    const float4* wr = (const float4*)(qk + (size_t)b * DD);
    float acc = 0.f;
    #pragma unroll
    for (int j = 0; j < 3; ++j) {
        float4 a = xr[lane + 64 * j];
        float4 w = wr[lane + 64 * j];
        acc += a.x * w.x + a.y * w.y + a.z * w.z + a.w * w.w;
    }
    acc = wave_reduce_sum(acc);
    if (lane == 0) {
        float lg = (acc + qbk[b]) * SCALE;
        logits[gw] = mask[gw] ? lg : -INFINITY;
    }
}

// Per batch: gates=sigmoid(logits), pos=suffix-cumsum, clamp, CoPE interp, softmax -> attn.
// One block of 256 threads per batch; each thread owns 8 consecutive t.
__global__ __launch_bounds__(256) void k_scan(const float* __restrict__ logits,
        const float* __restrict__ lint, float* __restrict__ attn) {
    int b = blockIdx.x, tid = threadIdx.x;
    __shared__ float lg[SS];
    __shared__ float li[NPOS];
    __shared__ float sa[256], sb[256];
    for (int i = tid; i < SS; i += 256) lg[i] = logits[b * SS + i];
    for (int i = tid; i < NPOS; i += 256) li[i] = lint[b * NPOS + i];
    __syncthreads();
    int base = tid * 8;
    float loc[8];
    float run = 0.f;
    #pragma unroll
    for (int k = 7; k >= 0; --k) {          // suffix sum within own chunk
        float v = lg[base + k];
        float gk = 1.f / (1.f + expf(-v));  // sigmoid; -inf -> 0
        run += gk;
        loc[k] = run;
    }
    sa[tid] = run;
    __syncthreads();
    // Hillis-Steele inclusive SUFFIX scan over 256 chunk totals (ping-pong)
    float* src = sa; float* dst = sb;
    for (int off = 1; off < 256; off <<= 1) {
        float v = src[tid];
        if (tid + off < 256) v += src[tid + off];
        dst[tid] = v;
        __syncthreads();
        float* t_ = src; src = dst; dst = t_;
    }
    float st = (tid < 255) ? src[tid + 1] : 0.f;  // exclusive suffix of later chunks
    // CoPE-adjusted logits
    float adj[8];
    float m = -INFINITY;
    #pragma unroll
    for (int k = 0; k < 8; ++k) {
        float v = lg[base + k];
        float nv;
        if (v == -INFINITY) {
            nv = v;                         // masked stays -inf
        } else {
            float p = fminf(loc[k] + st, (float)(NPOS - 1));
            float pf = floorf(p);
            float w = p - pf;
            int fi = (int)pf;
            int ci = (int)ceilf(p);
            nv = v + li[ci] * w + li[fi] * (1.f - w);
        }
        adj[k] = nv;
        m = fmaxf(m, nv);
    }
    __syncthreads();            // st reads of sa done; safe to reuse
    sa[tid] = m;
    __syncthreads();
    for (int s2 = 128; s2 > 0; s2 >>= 1) {
        if (tid < s2) sa[tid] = fmaxf(sa[tid], sa[tid + s2]);
        __syncthreads();
    }
    float bm = sa[0];
    __syncthreads();
    float sum = 0.f;
    #pragma unroll
    for (int k = 0; k < 8; ++k) { adj[k] = expf(adj[k] - bm); sum += adj[k]; }
    sa[tid] = sum;
    __syncthreads();
    for (int s2 = 128; s2 > 0; s2 >>= 1) {
        if (tid < s2) sa[tid] += sa[tid + s2];
        __syncthreads();
    }
    float inv = 1.f / sa[0];
    float4* out4 = (float4*)(attn + b * SS + base);
    out4[0] = make_float4(adj[0] * inv, adj[1] * inv, adj[2] * inv, adj[3] * inv);
    out4[1] = make_float4(adj[4] * inv, adj[5] * inv, adj[6] * inv, adj[7] * inv);
}

// Partial attn-weighted row sums: part[b,tc,e] = sum_{t in chunk tc} attn[b,t]*x[b,t,e]
// grid (TC, B), 192 threads (192 float4 = 768 floats per row).
__global__ __launch_bounds__(192) void k_ctx_part(const float* __restrict__ x,
        const float* __restrict__ attn, float* __restrict__ part) {
    int tc = blockIdx.x, b = blockIdx.y, tid = threadIdx.x;
    const int TPC = SS / TC;  // 32
    float4 acc = make_float4(0.f, 0.f, 0.f, 0.f);
    const float4* xr = (const float4*)(x + ((size_t)b * SS + (size_t)tc * TPC) * DD);
    const float* at = attn + b * SS + tc * TPC;
    for (int i = 0; i < TPC; ++i) {
        float a = at[i];
        float4 xv = xr[(size_t)i * 192 + tid];
        acc.x += a * xv.x; acc.y += a * xv.y; acc.z += a * xv.z; acc.w += a * xv.w;
    }
    ((float4*)(part + (size_t)(b * TC + tc) * DD))[tid] = acc;
}

// ctx[b,e] = sum_tc part[b,tc,e]
__global__ __launch_bounds__(256) void k_ctx_red(const float* __restrict__ part,
        float* __restrict__ ctx) {
    int idx = blockIdx.x * 256 + threadIdx.x;  // 0..6143
    if (idx >= BB * DD) return;
    int b = idx / DD, e = idx % DD;
    float acc = 0.f;
    #pragma unroll 4
    for (int tc = 0; tc < TC; ++tc) acc += part[(size_t)(b * TC + tc) * DD + e];
    ctx[idx] = acc;
}

extern "C" void kernel_launch(void* const* d_in, const int* in_sizes, int n_in,
                              void* d_out, int out_size, void* d_ws, size_t ws_size,
                              hipStream_t stream) {
    const float* x       = (const float*)d_in[0];  // [B,S,D]
    const int*   mask    = (const int*)  d_in[1];  // [B,S]
    const float* Wq      = (const float*)d_in[2];
    const float* bq      = (const float*)d_in[3];
    const float* Wk      = (const float*)d_in[4];
    const float* bk      = (const float*)d_in[5];
    const float* Wv      = (const float*)d_in[6];
    const float* bv      = (const float*)d_in[7];
    const float* pos_emb = (const float*)d_in[8];  // [D,NPOS]
    float* out = (float*)d_out;                    // [B,D]

    float* ws     = (float*)d_ws;
    float* q      = ws + WS_Q;
    float* qk     = ws + WS_QK;
    float* lint   = ws + WS_LI;
    float* logits = ws + WS_LOGITS;
    float* attn   = ws + WS_ATTN;
    float* ctx    = ws + WS_CTX;
    float* qbk    = ws + WS_QBK;
    float* part   = ws + WS_PART;

    // 1. q[b,d] from row s=0 of each batch
    k_gemv<<<dim3((BB * DD) / 4), dim3(256), 0, stream>>>(x, (size_t)SS * DD, Wq, bq, q);
    // 2. qk = q @ Wk (col-reduce), qbk = q.bk, lint = q @ pos_emb
    k_qk<<<dim3(5, BB), dim3(256), 0, stream>>>(q, Wk, bk, pos_emb, qk, qbk, lint);
    // 3. logits[b,t]  (pass 1 over x, 50 MB)
    k_logits<<<dim3((BB * SS) / 4), dim3(256), 0, stream>>>(x, qk, qbk, mask, logits);
    // 4. CoPE scan + softmax -> attn
    k_scan<<<dim3(BB), dim3(256), 0, stream>>>(logits, lint, attn);
    // 5. ctx partials (pass 2 over x, L3-hot)
    k_ctx_part<<<dim3(TC, BB), dim3(192), 0, stream>>>(x, attn, part);
    // 6. reduce partials
    k_ctx_red<<<dim3((BB * DD + 255) / 256), dim3(256), 0, stream>>>(part, ctx);
    // 7. out = ctx @ Wv.T + bv
    k_gemv<<<dim3((BB * DD) / 4), dim3(256), 0, stream>>>(ctx, (size_t)DD, Wv, bv, out);
}

// Round 2
// 49.801 us; speedup vs baseline: 2.1670x; 2.1670x over previous
//
#include <hip/hip_runtime.h>
#include <hip/hip_bf16.h>
#include <math.h>

// Problem constants
#define BB 8
#define SS 2048
#define DD 768
#define NPOS 512
#define TC 64              // t-chunks for ctx partial reduction (32 t each)
#define DSPLIT 16          // d-splits for the q@W mini-GEMM
#define DCHUNK (DD / DSPLIT)   // 48
#define ETOT 1280          // 768 (Wk cols) + 512 (pos_emb cols)
#define SCALE 0.036084391824351615f   // 1/sqrt(768)

// Workspace layout (float offsets, all 16B-aligned)
#define WS_Q      0        // 6144
#define WS_QK     6144     // 6144
#define WS_LI     12288    // 4096   (logits_int [B,NPOS])
#define WS_LOGITS 16384    // 16384  ([B,S], masked -> -inf)
#define WS_ATTN   32768    // 16384
#define WS_CTX    49152    // 6144
#define WS_PART   55296    // 8*64*768 = 393216
#define WS_PWS    448512   // DSPLIT*BB*ETOT = 163840
// total = 612352 floats = 2.45 MB

__device__ __forceinline__ float wave_reduce_sum(float v) {
    #pragma unroll
    for (int off = 32; off > 0; off >>= 1) v += __shfl_xor(v, off, 64);
    return v;
}

// out[b*768+d] = dot(vecs + b*vstride, W[d,:]) + bias[d]; wave per output.
__global__ __launch_bounds__(256) void k_gemv(const float* __restrict__ vecs, size_t vstride,
        const float* __restrict__ W, const float* __restrict__ bias,
        float* __restrict__ out) {
    int gw = (blockIdx.x * 256 + threadIdx.x) >> 6;
    int lane = threadIdx.x & 63;
    if (gw >= BB * DD) return;
    int b = gw / DD, d = gw % DD;
    const float4* vr = (const float4*)(vecs + (size_t)b * vstride);
    const float4* wr = (const float4*)(W + (size_t)d * DD);
    float acc = 0.f;
    #pragma unroll
    for (int j = 0; j < 3; ++j) {   // 3*64 float4 = 768 floats
        float4 a = vr[lane + 64 * j];
        float4 w = wr[lane + 64 * j];
        acc += a.x * w.x + a.y * w.y + a.z * w.z + a.w * w.w;
    }
    acc = wave_reduce_sum(acc);
    if (lane == 0) out[gw] = acc + bias[d];
}

// Partial q@W for W = concat(Wk cols, pos_emb cols).
// grid (5, DSPLIT): blockIdx.x 0..2 -> Wk e-chunks of 256; 3..4 -> pos_emb chunks.
// Each thread owns one column e, accumulates 8 batches over DCHUNK rows.
__global__ __launch_bounds__(256) void k_qkw(const float* __restrict__ q,
        const float* __restrict__ Wk, const float* __restrict__ pos_emb,
        float* __restrict__ pws) {
    int part = blockIdx.x, ds = blockIdx.y, tid = threadIdx.x;
    __shared__ float qs[BB][DCHUNK];
    for (int i = tid; i < BB * DCHUNK; i += 256) {
        int b = i / DCHUNK, d = i % DCHUNK;
        qs[b][d] = q[b * DD + ds * DCHUNK + d];
    }
    __syncthreads();
    const float* Wsrc; int stride, eg;
    if (part < 3) { Wsrc = Wk; stride = DD; eg = part * 256 + tid; }
    else { Wsrc = pos_emb; stride = NPOS; eg = DD + (part - 3) * 256 + tid; }
    int e = (part < 3) ? eg : eg - DD;
    const float* col = Wsrc + (size_t)(ds * DCHUNK) * stride + e;
    float acc[BB];
    #pragma unroll
    for (int b = 0; b < BB; ++b) acc[b] = 0.f;
    #pragma unroll
    for (int d = 0; d < DCHUNK; ++d) {
        float w = col[(size_t)d * stride];
        #pragma unroll
        for (int b = 0; b < BB; ++b) acc[b] += qs[b][d] * w;
    }
    #pragma unroll
    for (int b = 0; b < BB; ++b)
        pws[((size_t)ds * BB + b) * ETOT + eg] = acc[b];
}

// Reduce DSPLIT partials -> qk[b,0:768], lint[b,0:512]
__global__ __launch_bounds__(256) void k_qkr(const float* __restrict__ pws,
        float* __restrict__ qk, float* __restrict__ lint) {
    int idx = blockIdx.x * 256 + threadIdx.x;   // 0 .. 8*1280-1
    if (idx >= BB * ETOT) return;
    int b = idx / ETOT, e = idx % ETOT;
    float acc = 0.f;
    #pragma unroll
    for (int ds = 0; ds < DSPLIT; ++ds)
        acc += pws[((size_t)ds * BB + b) * ETOT + e];
    if (e < DD) qk[b * DD + e] = acc;
    else lint[b * NPOS + (e - DD)] = acc;
}

// logits[b,t] = scale * (x[b,t,:].qk[b,:] + q[b,:].bk); masked -> -inf. Wave per row.
__global__ __launch_bounds__(256) void k_logits(const float* __restrict__ x,
        const float* __restrict__ qk, const float* __restrict__ q,
        const float* __restrict__ bk,
        const int* __restrict__ mask, float* __restrict__ logits) {
    int gw = (blockIdx.x * 256 + threadIdx.x) >> 6;
    int lane = threadIdx.x & 63;
    if (gw >= BB * SS) return;
    int b = gw / SS;
    const float4* xr = (const float4*)(x + (size_t)gw * DD);
    const float4* wr = (const float4*)(qk + (size_t)b * DD);
    const float4* qr = (const float4*)(q + (size_t)b * DD);
    const float4* br = (const float4*)bk;
    float acc = 0.f;
    #pragma unroll
    for (int j = 0; j < 3; ++j) {
        float4 a = xr[lane + 64 * j];
        float4 w = wr[lane + 64 * j];
        acc += a.x * w.x + a.y * w.y + a.z * w.z + a.w * w.w;
        float4 qv = qr[lane + 64 * j];
        float4 bv = br[lane + 64 * j];
        acc += qv.x * bv.x + qv.y * bv.y + qv.z * bv.z + qv.w * bv.w;
    }
    acc = wave_reduce_sum(acc);
    if (lane == 0) {
        float lg = acc * SCALE;
        logits[gw] = mask[gw] ? lg : -INFINITY;
    }
}

// Per batch: gates=sigmoid(logits), pos=suffix-cumsum, clamp, CoPE interp, softmax -> attn.
__global__ __launch_bounds__(256) void k_scan(const float* __restrict__ logits,
        const float* __restrict__ lint, float* __restrict__ attn) {
    int b = blockIdx.x, tid = threadIdx.x;
    __shared__ float lg[SS];
    __shared__ float li[NPOS];
    __shared__ float sa[256], sb[256];
    for (int i = tid; i < SS; i += 256) lg[i] = logits[b * SS + i];
    for (int i = tid; i < NPOS; i += 256) li[i] = lint[b * NPOS + i];
    __syncthreads();
    int base = tid * 8;
    float loc[8];
    float run = 0.f;
    #pragma unroll
    for (int k = 7; k >= 0; --k) {          // suffix sum within own chunk
        float v = lg[base + k];
        float gk = 1.f / (1.f + expf(-v));  // sigmoid; -inf -> 0
        run += gk;
        loc[k] = run;
    }
    sa[tid] = run;
    __syncthreads();
    // Hillis-Steele inclusive SUFFIX scan over 256 chunk totals (ping-pong)
    float* src = sa; float* dst = sb;
    for (int off = 1; off < 256; off <<= 1) {
        float v = src[tid];
        if (tid + off < 256) v += src[tid + off];
        dst[tid] = v;
        __syncthreads();
        float* t_ = src; src = dst; dst = t_;
    }
    float st = (tid < 255) ? src[tid + 1] : 0.f;  // exclusive suffix of later chunks
    float adj[8];
    float m = -INFINITY;
    #pragma unroll
    for (int k = 0; k < 8; ++k) {
        float v = lg[base + k];
        float nv;
        if (v == -INFINITY) {
            nv = v;
        } else {
            float p = fminf(loc[k] + st, (float)(NPOS - 1));
            float pf = floorf(p);
            float w = p - pf;
            int fi = (int)pf;
            int ci = (int)ceilf(p);
            nv = v + li[ci] * w + li[fi] * (1.f - w);
        }
        adj[k] = nv;
        m = fmaxf(m, nv);
    }
    __syncthreads();
    sa[tid] = m;
    __syncthreads();
    for (int s2 = 128; s2 > 0; s2 >>= 1) {
        if (tid < s2) sa[tid] = fmaxf(sa[tid], sa[tid + s2]);
        __syncthreads();
    }
    float bm = sa[0];
    __syncthreads();
    float sum = 0.f;
    #pragma unroll
    for (int k = 0; k < 8; ++k) { adj[k] = expf(adj[k] - bm); sum += adj[k]; }
    sa[tid] = sum;
    __syncthreads();
    for (int s2 = 128; s2 > 0; s2 >>= 1) {
        if (tid < s2) sa[tid] += sa[tid + s2];
        __syncthreads();
    }
    float inv = 1.f / sa[0];
    float4* out4 = (float4*)(attn + b * SS + base);
    out4[0] = make_float4(adj[0] * inv, adj[1] * inv, adj[2] * inv, adj[3] * inv);
    out4[1] = make_float4(adj[4] * inv, adj[5] * inv, adj[6] * inv, adj[7] * inv);
}

// Partial attn-weighted row sums: part[b,tc,e] = sum_{t in chunk tc} attn[b,t]*x[b,t,e]
__global__ __launch_bounds__(192) void k_ctx_part(const float* __restrict__ x,
        const float* __restrict__ attn, float* __restrict__ part) {
    int tc = blockIdx.x, b = blockIdx.y, tid = threadIdx.x;
    const int TPC = SS / TC;  // 32
    float4 acc = make_float4(0.f, 0.f, 0.f, 0.f);
    const float4* xr = (const float4*)(x + ((size_t)b * SS + (size_t)tc * TPC) * DD);
    const float* at = attn + b * SS + tc * TPC;
    for (int i = 0; i < TPC; ++i) {
        float a = at[i];
        float4 xv = xr[(size_t)i * 192 + tid];
        acc.x += a * xv.x; acc.y += a * xv.y; acc.z += a * xv.z; acc.w += a * xv.w;
    }
    ((float4*)(part + (size_t)(b * TC + tc) * DD))[tid] = acc;
}

// ctx[b,e] = sum_tc part[b,tc,e]
__global__ __launch_bounds__(256) void k_ctx_red(const float* __restrict__ part,
        float* __restrict__ ctx) {
    int idx = blockIdx.x * 256 + threadIdx.x;  // 0..6143
    if (idx >= BB * DD) return;
    int b = idx / DD, e = idx % DD;
    float acc = 0.f;
    #pragma unroll 4
    for (int tc = 0; tc < TC; ++tc) acc += part[(size_t)(b * TC + tc) * DD + e];
    ctx[idx] = acc;
}

extern "C" void kernel_launch(void* const* d_in, const int* in_sizes, int n_in,
                              void* d_out, int out_size, void* d_ws, size_t ws_size,
                              hipStream_t stream) {
    const float* x       = (const float*)d_in[0];  // [B,S,D]
    const int*   mask    = (const int*)  d_in[1];  // [B,S]
    const float* Wq      = (const float*)d_in[2];
    const float* bq      = (const float*)d_in[3];
    const float* Wk      = (const float*)d_in[4];
    const float* bk      = (const float*)d_in[5];
    const float* Wv      = (const float*)d_in[6];
    const float* bv      = (const float*)d_in[7];
    const float* pos_emb = (const float*)d_in[8];  // [D,NPOS]
    float* out = (float*)d_out;                    // [B,D]

    float* ws     = (float*)d_ws;
    float* q      = ws + WS_Q;
    float* qk     = ws + WS_QK;
    float* lint   = ws + WS_LI;
    float* logits = ws + WS_LOGITS;
    float* attn   = ws + WS_ATTN;
    float* ctx    = ws + WS_CTX;
    float* part   = ws + WS_PART;
    float* pws    = ws + WS_PWS;

    // 1. q[b,d] from row s=0 of each batch
    k_gemv<<<dim3((BB * DD) / 4), dim3(256), 0, stream>>>(x, (size_t)SS * DD, Wq, bq, q);
    // 2. partial q @ [Wk | pos_emb]  (batch-shared W reads, 16-way d-split)
    k_qkw<<<dim3(5, DSPLIT), dim3(256), 0, stream>>>(q, Wk, pos_emb, pws);
    // 3. reduce partials -> qk, lint
    k_qkr<<<dim3((BB * ETOT + 255) / 256), dim3(256), 0, stream>>>(pws, qk, lint);
    // 4. logits[b,t] (pass 1 over x), with q.bk folded in
    k_logits<<<dim3((BB * SS) / 4), dim3(256), 0, stream>>>(x, qk, q, bk, mask, logits);
    // 5. CoPE scan + softmax -> attn
    k_scan<<<dim3(BB), dim3(256), 0, stream>>>(logits, lint, attn);
    // 6. ctx partials (pass 2 over x)
    k_ctx_part<<<dim3(TC, BB), dim3(192), 0, stream>>>(x, attn, part);
    // 7. reduce partials
    k_ctx_red<<<dim3((BB * DD + 255) / 256), dim3(256), 0, stream>>>(part, ctx);
    // 8. out = ctx @ Wv.T + bv
    k_gemv<<<dim3((BB * DD) / 4), dim3(256), 0, stream>>>(ctx, (size_t)DD, Wv, bv, out);
}

// Round 3
// 46.380 us; speedup vs baseline: 2.3268x; 1.0738x over previous
//
#include <hip/hip_runtime.h>
#include <hip/hip_bf16.h>
#include <math.h>

// Problem constants
#define BB 8
#define SS 2048
#define DD 768
#define NPOS 512
#define TC 64                 // t-chunks for ctx partial accumulation (32 t each)
#define DSPLIT 32             // d-splits for the q@W mini-GEMM
#define DCHUNK (DD / DSPLIT)  // 24
#define SCALE 0.036084391824351615f   // 1/sqrt(768)

// Workspace layout (float offsets, 16B-aligned)
#define WS_Q      0        // 6144
#define WS_QK     6144     // 6144  (atomic-accumulated; contiguous with lint)
#define WS_LI     12288    // 4096
#define WS_QBK    16384    // 16 (8 used)
#define WS_LOGITS 16400    // 16384
#define WS_ATTN   32784    // 16384
#define WS_CTX    49168    // 6144  (atomic-accumulated)
// total 55312 floats = 221 KB

__device__ __forceinline__ float wave_sum(float v) {
    #pragma unroll
    for (int off = 32; off > 0; off >>= 1) v += __shfl_xor(v, off, 64);
    return v;
}
__device__ __forceinline__ float wave_max(float v) {
    #pragma unroll
    for (int off = 32; off > 0; off >>= 1) v = fmaxf(v, __shfl_xor(v, off, 64));
    return v;
}

// q[b,d] = x[b,0,:].Wq[d,:] + bq[d]; wave per output. Also zeros qk+lint (10240 floats).
__global__ __launch_bounds__(256) void k_q(const float* __restrict__ x,
        const float* __restrict__ Wq, const float* __restrict__ bq,
        float* __restrict__ q, float* __restrict__ qkz) {
    int zi = blockIdx.x * 256 + threadIdx.x;
    if (zi < DD * BB + NPOS * BB) qkz[zi] = 0.f;   // zero qk (6144) + lint (4096)
    int gw = zi >> 6;
    int lane = threadIdx.x & 63;
    if (gw >= BB * DD) return;
    int b = gw / DD, d = gw % DD;
    const float4* vr = (const float4*)(x + (size_t)b * SS * DD);
    const float4* wr = (const float4*)(Wq + (size_t)d * DD);
    float acc = 0.f;
    #pragma unroll
    for (int j = 0; j < 3; ++j) {
        float4 a = vr[lane + 64 * j];
        float4 w = wr[lane + 64 * j];
        acc += a.x * w.x + a.y * w.y + a.z * w.z + a.w * w.w;
    }
    acc = wave_sum(acc);
    if (lane == 0) q[gw] = acc + bq[d];
}

// Partial q@[Wk | pos_emb], atomic-accumulated into qk/lint.
// grid (5, DSPLIT): x 0..2 -> Wk e-chunks of 256; 3..4 -> pos_emb chunks.
// Block (0,0) additionally computes qbk[b] = q[b,:].bk.
__global__ __launch_bounds__(256) void k_qkw(const float* __restrict__ q,
        const float* __restrict__ Wk, const float* __restrict__ pos_emb,
        const float* __restrict__ bk,
        float* __restrict__ qk, float* __restrict__ lint, float* __restrict__ qbk) {
    int part = blockIdx.x, ds = blockIdx.y, tid = threadIdx.x;
    __shared__ float qs[BB][DCHUNK];
    for (int i = tid; i < BB * DCHUNK; i += 256) {
        int b = i / DCHUNK, d = i % DCHUNK;
        qs[b][d] = q[b * DD + ds * DCHUNK + d];
    }
    __syncthreads();
    const float* Wsrc; int stride; float* dst; int e;
    if (part < 3) { Wsrc = Wk; stride = DD; dst = qk; e = part * 256 + tid; }
    else { Wsrc = pos_emb; stride = NPOS; dst = lint; e = (part - 3) * 256 + tid; }
    int ncols = (part < 3) ? DD : NPOS;
    const float* col = Wsrc + (size_t)(ds * DCHUNK) * stride + e;
    float acc[BB];
    #pragma unroll
    for (int b = 0; b < BB; ++b) acc[b] = 0.f;
    #pragma unroll
    for (int d = 0; d < DCHUNK; ++d) {
        float w = col[(size_t)d * stride];
        #pragma unroll
        for (int b = 0; b < BB; ++b) acc[b] += qs[b][d] * w;
    }
    #pragma unroll
    for (int b = 0; b < BB; ++b) atomicAdd(&dst[b * ncols + e], acc[b]);
    // qbk: one block, 4 waves x 2 batches each
    if (part == 0 && ds == 0) {
        int w = tid >> 6, lane = tid & 63;
        #pragma unroll
        for (int r = 0; r < 2; ++r) {
            int b = w + 4 * r;
            float p = 0.f;
            #pragma unroll
            for (int j = 0; j < 12; ++j)
                p += q[b * DD + lane + 64 * j] * bk[lane + 64 * j];
            p = wave_sum(p);
            if (lane == 0) qbk[b] = p;
        }
    }
}

// logits[b,t] = scale * (x[b,t,:].qk[b,:] + qbk[b]); masked -> -inf. Wave per row.
__global__ __launch_bounds__(256) void k_logits(const float* __restrict__ x,
        const float* __restrict__ qk, const float* __restrict__ qbk,
        const int* __restrict__ mask, float* __restrict__ logits) {
    int gw = (blockIdx.x * 256 + threadIdx.x) >> 6;
    int lane = threadIdx.x & 63;
    if (gw >= BB * SS) return;
    int b = gw / SS;
    const float4* xr = (const float4*)(x + (size_t)gw * DD);
    const float4* wr = (const float4*)(qk + (size_t)b * DD);
    float acc = 0.f;
    #pragma unroll
    for (int j = 0; j < 3; ++j) {
        float4 a = xr[lane + 64 * j];
        float4 w = wr[lane + 64 * j];
        acc += a.x * w.x + a.y * w.y + a.z * w.z + a.w * w.w;
    }
    acc = wave_sum(acc);
    if (lane == 0) {
        float lg = (acc + qbk[b]) * SCALE;
        logits[gw] = mask[gw] ? lg : -INFINITY;
    }
}

// Per batch: sigmoid gates, suffix-cumsum positions, CoPE interp, softmax -> attn.
// One block of 256 threads (4 waves) per batch; thread owns 8 consecutive t.
// Wave-shuffle scan: 3 __syncthreads total. Also zeros ctx[b,:].
__global__ __launch_bounds__(256) void k_scan(const float* __restrict__ logits,
        const float* __restrict__ lint, float* __restrict__ attn,
        float* __restrict__ ctx) {
    int b = blockIdx.x, tid = threadIdx.x;
    int w = tid >> 6, lane = tid & 63;
    __shared__ float li[NPOS];
    __shared__ float swt[4], smax[4], ssum[4];
    // zero ctx for the atomic pass-2
    #pragma unroll
    for (int j = 0; j < 3; ++j) ctx[b * DD + tid + 256 * j] = 0.f;
    // cooperative li load (2 per thread)
    for (int i = tid; i < NPOS; i += 256) li[i] = lint[b * NPOS + i];
    // own 8 logits straight to registers
    int base = tid * 8;
    const float4* lg4 = (const float4*)(logits + b * SS + base);
    float4 l0 = lg4[0], l1 = lg4[1];
    float lg[8] = {l0.x, l0.y, l0.z, l0.w, l1.x, l1.y, l1.z, l1.w};
    // suffix sum of gates within own chunk
    float loc[8];
    float run = 0.f;
    #pragma unroll
    for (int k = 7; k >= 0; --k) {
        float gk = 1.f / (1.f + expf(-lg[k]));  // sigmoid; -inf -> 0
        run += gk;
        loc[k] = run;
    }
    // wave inclusive suffix scan of chunk totals (no barrier)
    float v = run;
    #pragma unroll
    for (int off = 1; off < 64; off <<= 1) {
        float o = __shfl_down(v, off, 64);
        if (lane + off < 64) v += o;
    }
    float sufExcl = (lane < 63) ? __shfl_down(v, 1, 64) : 0.f;
    if (lane == 0) swt[w] = v;          // wave total
    __syncthreads();                    // swt ready; li ready
    float wsuf = 0.f;
    for (int ww = w + 1; ww < 4; ++ww) wsuf += swt[ww];
    float st = sufExcl + wsuf;          // suffix of all later chunks
    // CoPE-adjusted logits
    float adj[8];
    float m = -INFINITY;
    #pragma unroll
    for (int k = 0; k < 8; ++k) {
        float val = lg[k];
        float nv;
        if (val == -INFINITY) {
            nv = val;
        } else {
            float p = fminf(loc[k] + st, (float)(NPOS - 1));
            float pf = floorf(p);
            float wt = p - pf;
            int fi = (int)pf;
            int ci = (int)ceilf(p);
            nv = val + li[ci] * wt + li[fi] * (1.f - wt);
        }
        adj[k] = nv;
        m = fmaxf(m, nv);
    }
    // block max: wave max + LDS combine
    m = wave_max(m);
    if (lane == 0) smax[w] = m;
    __syncthreads();
    float bm = fmaxf(fmaxf(smax[0], smax[1]), fmaxf(smax[2], smax[3]));
    // exp + block sum
    float sum = 0.f;
    #pragma unroll
    for (int k = 0; k < 8; ++k) { adj[k] = expf(adj[k] - bm); sum += adj[k]; }
    sum = wave_sum(sum);
    if (lane == 0) ssum[w] = sum;
    __syncthreads();
    float inv = 1.f / (ssum[0] + ssum[1] + ssum[2] + ssum[3]);
    float4* out4 = (float4*)(attn + b * SS + base);
    out4[0] = make_float4(adj[0] * inv, adj[1] * inv, adj[2] * inv, adj[3] * inv);
    out4[1] = make_float4(adj[4] * inv, adj[5] * inv, adj[6] * inv, adj[7] * inv);
}

// attn-weighted row sums, atomic-accumulated into ctx. grid (TC, B), 192 threads.
__global__ __launch_bounds__(192) void k_ctx_part(const float* __restrict__ x,
        const float* __restrict__ attn, float* __restrict__ ctx) {
    int tc = blockIdx.x, b = blockIdx.y, tid = threadIdx.x;
    const int TPC = SS / TC;  // 32
    float4 acc = make_float4(0.f, 0.f, 0.f, 0.f);
    const float4* xr = (const float4*)(x + ((size_t)b * SS + (size_t)tc * TPC) * DD);
    const float* at = attn + b * SS + tc * TPC;
    for (int i = 0; i < TPC; ++i) {
        float a = at[i];
        float4 xv = xr[(size_t)i * 192 + tid];
        acc.x += a * xv.x; acc.y += a * xv.y; acc.z += a * xv.z; acc.w += a * xv.w;
    }
    float* dst = ctx + b * DD + tid * 4;
    atomicAdd(dst + 0, acc.x);
    atomicAdd(dst + 1, acc.y);
    atomicAdd(dst + 2, acc.z);
    atomicAdd(dst + 3, acc.w);
}

// out[b,d] = ctx[b,:].Wv[d,:] + bv[d]; wave per output.
__global__ __launch_bounds__(256) void k_out(const float* __restrict__ ctx,
        const float* __restrict__ Wv, const float* __restrict__ bv,
        float* __restrict__ out) {
    int gw = (blockIdx.x * 256 + threadIdx.x) >> 6;
    int lane = threadIdx.x & 63;
    if (gw >= BB * DD) return;
    int b = gw / DD, d = gw % DD;
    const float4* vr = (const float4*)(ctx + (size_t)b * DD);
    const float4* wr = (const float4*)(Wv + (size_t)d * DD);
    float acc = 0.f;
    #pragma unroll
    for (int j = 0; j < 3; ++j) {
        float4 a = vr[lane + 64 * j];
        float4 w = wr[lane + 64 * j];
        acc += a.x * w.x + a.y * w.y + a.z * w.z + a.w * w.w;
    }
    acc = wave_sum(acc);
    if (lane == 0) out[gw] = acc + bv[d];
}

extern "C" void kernel_launch(void* const* d_in, const int* in_sizes, int n_in,
                              void* d_out, int out_size, void* d_ws, size_t ws_size,
                              hipStream_t stream) {
    const float* x       = (const float*)d_in[0];  // [B,S,D]
    const int*   mask    = (const int*)  d_in[1];  // [B,S]
    const float* Wq      = (const float*)d_in[2];
    const float* bq      = (const float*)d_in[3];
    const float* Wk      = (const float*)d_in[4];
    const float* bk      = (const float*)d_in[5];
    const float* Wv      = (const float*)d_in[6];
    const float* bv      = (const float*)d_in[7];
    const float* pos_emb = (const float*)d_in[8];  // [D,NPOS]
    float* out = (float*)d_out;                    // [B,D]

    float* ws     = (float*)d_ws;
    float* q      = ws + WS_Q;
    float* qk     = ws + WS_QK;
    float* lint   = ws + WS_LI;
    float* qbk    = ws + WS_QBK;
    float* logits = ws + WS_LOGITS;
    float* attn   = ws + WS_ATTN;
    float* ctx    = ws + WS_CTX;

    // 1. q from row s=0; zero qk/lint for atomic accumulation
    k_q<<<dim3((BB * DD) / 4), dim3(256), 0, stream>>>(x, Wq, bq, q, qk);
    // 2. q @ [Wk | pos_emb] -> qk, lint (atomic); qbk scalar
    k_qkw<<<dim3(5, DSPLIT), dim3(256), 0, stream>>>(q, Wk, pos_emb, bk, qk, lint, qbk);
    // 3. logits (pass 1 over x, 50 MB)
    k_logits<<<dim3((BB * SS) / 4), dim3(256), 0, stream>>>(x, qk, qbk, mask, logits);
    // 4. CoPE scan + softmax -> attn; zero ctx
    k_scan<<<dim3(BB), dim3(256), 0, stream>>>(logits, lint, attn, ctx);
    // 5. ctx = attn-weighted row sums (pass 2 over x, atomic)
    k_ctx_part<<<dim3(TC, BB), dim3(192), 0, stream>>>(x, attn, ctx);
    // 6. out = ctx @ Wv.T + bv
    k_out<<<dim3((BB * DD) / 4), dim3(256), 0, stream>>>(ctx, Wv, bv, out);
}